// Round 6
// baseline (65.890 us; speedup 1.0000x reference)
//
#include <hip/hip_runtime.h>
#include <hip/hip_bf16.h>

// CosSim2D: inputs (32,64,64,64) f32, w (1,576,128) f32, p (128), q (1)
// out (32,64,64,128) f32.
// R6: N-split blocks. Block = 2 output rows x 64 px x 64 kernels (half N).
// Grid 2048 = 8 blocks/CU over 2 rounds -> phase turnover overlaps store
// drain with compute. All 4 waves stream the SAME 72KB B-half (L1 temporal
// sharing, per-tap barrier lockstep). Nontemporal output stores.

typedef short bf16x8 __attribute__((ext_vector_type(8)));
typedef float f32x4 __attribute__((ext_vector_type(4)));

__device__ __forceinline__ unsigned short f2bf(float f) {
    union { float f; unsigned int u; } v; v.f = f;
    unsigned int u = v.u;
    unsigned int r = (u + 0x7fffu + ((u >> 16) & 1u)) >> 16;  // RNE
    return (unsigned short)r;
}

// ---- pre-kernel: normalize w columns (fp32), store bf16 fragment-contiguous:
// wn2[((tap*2 + kc)*128 + n)*32 + koff] = w_hat[k = tap*64 + kc*32 + koff][n]
__global__ void prep_w_kernel(const float* __restrict__ w,
                              unsigned short* __restrict__ wn2) {
    const int n = blockIdx.x;
    const int lane = threadIdx.x;
    float vals[9];
    float s = 0.f;
#pragma unroll
    for (int i = 0; i < 9; ++i) {
        float v = w[(i * 64 + lane) * 128 + n];
        vals[i] = v;
        s += v * v;
    }
#pragma unroll
    for (int off = 1; off < 64; off <<= 1) s += __shfl_xor(s, off);
    const float inv = 1.0f / sqrtf(fmaxf(s, 1e-12f));
    const int kc = lane >> 5, koff = lane & 31;
#pragma unroll
    for (int i = 0; i < 9; ++i)
        wn2[((i * 2 + kc) * 128 + n) * 32 + koff] = f2bf(vals[i] * inv);
}

#define SLOT 4752   // 66*72 shorts per staged row

// ---- main: block = (image b, rows y0..y0+1, n-half nh); 128 px x 64 n
__global__ __launch_bounds__(256, 4) void cossim_main(
    const float* __restrict__ in, const unsigned short* __restrict__ wn,
    const float* __restrict__ p, const float* __restrict__ q,
    float* __restrict__ out) {
    // A: [4 rows][66 cols (zero-pad 0,65)][72 ch (64 + 16B pad)] bf16 = 38016 B
    __shared__ unsigned short A[4 * 66 * 72];
    __shared__ float rcsum[256];   // per-(row,col) fp32 square-sums
    __shared__ float xni[128];     // per-pixel 1/(||x||+q_eff)
    __shared__ float pfs[64];      // exp(p/P_SCALE) for this n-half

    const int tid = (int)threadIdx.x;
    // bijective XCD swizzle: 2048 blocks, 8 XCDs, 256 consecutive l per XCD.
    // nh toggles fastest -> the two n-half twins of a row-pair are adjacent
    // on the same XCD -> input rows L2-hit.
    const int l = ((int)blockIdx.x & 7) * 256 + ((int)blockIdx.x >> 3);
    const int sp = l >> 1, nh = l & 1;
    const int b = sp >> 5, y0 = (sp & 31) * 2;

    if (tid < 64) pfs[tid] = expf(p[nh * 64 + tid] * 0.2f);

    // ---- stage 4 input rows (y0-1 .. y0+2) + fused fp32 norm partials
    {
        const int r = tid >> 6;        // staged row 0..3
        const int col = tid & 63;
        const int row = y0 + r - 1;
        unsigned short* dst = &A[(r * 66 + col + 1) * 72];
        float s = 0.f;
        if ((unsigned)row < 64u) {
            const float4* src = reinterpret_cast<const float4*>(
                in + (size_t)b * 262144 + row * 4096 + col * 64);
#pragma unroll
            for (int it = 0; it < 8; ++it) {
                float4 v0 = src[2 * it];
                float4 v1 = src[2 * it + 1];
                s += v0.x * v0.x + v0.y * v0.y + v0.z * v0.z + v0.w * v0.w;
                s += v1.x * v1.x + v1.y * v1.y + v1.z * v1.z + v1.w * v1.w;
                union { float f; unsigned u; } ux, uy, uz, uw;
                uint4 pk;
                ux.f = v0.x; uy.f = v0.y; uz.f = v0.z; uw.f = v0.w;
                pk.x = __builtin_amdgcn_perm(uy.u + 0x8000u, ux.u + 0x8000u, 0x07060302u);
                pk.y = __builtin_amdgcn_perm(uw.u + 0x8000u, uz.u + 0x8000u, 0x07060302u);
                ux.f = v1.x; uy.f = v1.y; uz.f = v1.z; uw.f = v1.w;
                pk.z = __builtin_amdgcn_perm(uy.u + 0x8000u, ux.u + 0x8000u, 0x07060302u);
                pk.w = __builtin_amdgcn_perm(uw.u + 0x8000u, uz.u + 0x8000u, 0x07060302u);
                *reinterpret_cast<uint4*>(dst + it * 8) = pk;
            }
        } else {
            uint4 z; z.x = z.y = z.z = z.w = 0u;
#pragma unroll
            for (int it = 0; it < 8; ++it)
                *reinterpret_cast<uint4*>(dst + it * 8) = z;
        }
        rcsum[tid] = s;
    }
    if (tid < 64) {  // zero border cols 0 and 65, all 4 rows
        const int r = tid >> 4, side = (tid >> 3) & 1, ch = (tid & 7) * 8;
        uint4 z; z.x = z.y = z.z = z.w = 0u;
        *reinterpret_cast<uint4*>(&A[(r * 66 + side * 65) * 72 + ch]) = z;
    }
    __syncthreads();

    // ---- per-pixel 1/(||x||+q_eff) from fp32 partials
    if (tid < 128) {
        const int ry = tid >> 6, x = tid & 63;
        const float qe = expf(q[0] * (-1.0f / 0.3f));
        float s = 0.f;
#pragma unroll
        for (int dy = 0; dy < 3; ++dy) {
            const float* rs = &rcsum[(ry + dy) * 64];
            if (x > 0) s += rs[x - 1];
            s += rs[x];
            if (x < 63) s += rs[x + 1];
        }
        xni[tid] = 1.0f / (sqrtf(fmaxf(s, 1e-12f)) + qe);
    }
    // no barrier needed: the first in-loop barrier below covers xni visibility

    // ---- MFMA loop: 4 waves = 4 M-quarters, all share the same 64-n half
    const int wv = tid >> 6, lane = tid & 63;
    const int lr = lane & 15, lg = lane >> 4;
    const int rt = wv >> 1;            // row-in-tile 0..1
    const int xbase = (wv & 1) * 32;   // px-x base 0 or 32
    f32x4 acc[2][4] = {};
    const unsigned short* wB = wn + (nh * 64 + lr) * 32 + lg * 8;

#pragma unroll
    for (int dy = 0; dy < 3; ++dy) {
#pragma unroll
        for (int dx = 0; dx < 3; ++dx) {
            __syncthreads();   // lockstep: 8KB B working set per tap stays L1-hot
            const int tap = dy * 3 + dx;
#pragma unroll
            for (int kc = 0; kc < 2; ++kc) {
                const unsigned short* wt = wB + (tap * 2 + kc) * 4096;
                bf16x8 b0 = *reinterpret_cast<const bf16x8*>(wt);
                bf16x8 b1 = *reinterpret_cast<const bf16x8*>(wt + 512);
                bf16x8 b2 = *reinterpret_cast<const bf16x8*>(wt + 1024);
                bf16x8 b3 = *reinterpret_cast<const bf16x8*>(wt + 1536);
                const unsigned short* abase =
                    &A[((rt + dy) * 66 + xbase + lr + dx) * 72 + kc * 32 + lg * 8];
#pragma unroll
                for (int mf = 0; mf < 2; ++mf) {
                    bf16x8 av = *reinterpret_cast<const bf16x8*>(abase + mf * 16 * 72);
                    acc[mf][0] = __builtin_amdgcn_mfma_f32_16x16x32_bf16(av, b0, acc[mf][0], 0, 0, 0);
                    acc[mf][1] = __builtin_amdgcn_mfma_f32_16x16x32_bf16(av, b1, acc[mf][1], 0, 0, 0);
                    acc[mf][2] = __builtin_amdgcn_mfma_f32_16x16x32_bf16(av, b2, acc[mf][2], 0, 0, 0);
                    acc[mf][3] = __builtin_amdgcn_mfma_f32_16x16x32_bf16(av, b3, acc[mf][3], 0, 0, 0);
                }
            }
        }
    }

    // ---- epilogue: sim = acc * xni; out = sign * (|sim|+eps)^p_eff (NT stores)
    float* obase = out + (size_t)(b * 64 + y0 + rt) * 8192 + nh * 64;
#pragma unroll
    for (int mf = 0; mf < 2; ++mf) {
#pragma unroll
        for (int i = 0; i < 4; ++i) {
            const int x = xbase + mf * 16 + lg * 4 + i;   // C/D: row=(lane>>4)*4+reg
            const float xn = xni[rt * 64 + x];
#pragma unroll
            for (int nf = 0; nf < 4; ++nf) {
                const int nl = nf * 16 + lr;
                float sim = acc[mf][nf][i] * xn;
                float aa = fabsf(sim) + 1e-6f;
                float r = exp2f(pfs[nl] * log2f(aa));
                __builtin_nontemporal_store(copysignf(r, sim),
                                            &obase[(size_t)x * 128 + nl]);
            }
        }
    }
}

extern "C" void kernel_launch(void* const* d_in, const int* in_sizes, int n_in,
                              void* d_out, int out_size, void* d_ws, size_t ws_size,
                              hipStream_t stream) {
    (void)in_sizes; (void)n_in; (void)out_size; (void)ws_size;
    const float* in = (const float*)d_in[0];
    const float* w  = (const float*)d_in[1];
    const float* p  = (const float*)d_in[2];
    const float* q  = (const float*)d_in[3];
    float* out = (float*)d_out;
    unsigned short* wn = (unsigned short*)d_ws;  // 18*128*32 bf16 = 147456 B

    prep_w_kernel<<<128, 64, 0, stream>>>(w, wn);
    cossim_main<<<2048, 256, 0, stream>>>(in, wn, p, q, out);
}